// Round 10
// baseline (490.129 us; speedup 1.0000x reference)
//
#include <hip/hip_runtime.h>
#include <hip/hip_fp16.h>

#define N_NODES 100000
#define N_EDGES 1600000
#define F 128
#define H 16
#define C 40
#define NH (N_NODES * H)
#define NBKT 391   // buckets of 256 nodes: ceil(100000/256)
#define ABLK 256   // partition blocks
#define EPB 6250   // edges per partition block (256*6250 = 1.6M exact)
#define PROJB 1563 // proj1 blocks: ceil(100000/64)

__device__ __forceinline__ float cvh(ushort u) {
  return __half2float(__ushort_as_half(u));
}
__device__ __forceinline__ ushort pkh(float f) {
  return __half_as_ushort(__float2half(f));
}
__device__ __forceinline__ unsigned pk2(float lo, float hi) {
  return (unsigned)pkh(lo) | ((unsigned)pkh(hi) << 16);
}

// ---------------- CSR build 1: per-block bucket rows (plain stores) ---------
__global__ __launch_bounds__(256) void k_pcount(const int* __restrict__ dst,
                                                int* __restrict__ pc) {
  __shared__ int cnt[NBKT];
  for (int i = threadIdx.x; i < NBKT; i += 256) cnt[i] = 0;
  __syncthreads();
  const int e0 = blockIdx.x * EPB;
  for (int e = e0 + threadIdx.x; e < e0 + EPB; e += 256)
    atomicAdd(&cnt[dst[e] >> 8], 1);
  __syncthreads();
  for (int i = threadIdx.x; i < NBKT; i += 256)
    pc[blockIdx.x * NBKT + i] = cnt[i];
}

// ---------------- CSR build 2a: per-bucket column scan (391 parallel blocks)
// pc[b][t] -> exclusive prefix over b (LOCAL base); counts[t] = column total.
__global__ __launch_bounds__(256) void k_pscanA(int* __restrict__ pc,
                                                int* __restrict__ counts) {
  __shared__ int ls[256];
  const int t = blockIdx.x, tid = threadIdx.x;
  int v = pc[tid * NBKT + t];
  ls[tid] = v;
  __syncthreads();
  for (int off = 1; off < 256; off <<= 1) {
    int a = (tid >= off) ? ls[tid - off] : 0;
    __syncthreads();
    ls[tid] += a;
    __syncthreads();
  }
  pc[tid * NBKT + t] = ls[tid] - v;  // local exclusive base
  if (tid == 255) counts[t] = ls[255];
}

// ---------------- CSR build 2b: scan 391 bucket totals -> global starts -----
__global__ __launch_bounds__(512) void k_pscanB(const int* __restrict__ counts,
                                                int* __restrict__ starts) {
  __shared__ int ls[512];
  const int tid = threadIdx.x;
  int v = (tid < NBKT) ? counts[tid] : 0;
  ls[tid] = v;
  __syncthreads();
  for (int off = 1; off < 512; off <<= 1) {
    int a = (tid >= off) ? ls[tid - off] : 0;
    __syncthreads();
    ls[tid] += a;
    __syncthreads();
  }
  if (tid < NBKT) starts[tid] = ls[tid] - v;  // exclusive
}

// ---------------- CSR fill (blocks 0..255) fused with proj1 (rest) ----------
// pair = (dlocal<<17) | src  (dlocal<256 -> 8 bits; src<100000 -> 17 bits)
__global__ __launch_bounds__(256) void k_fill_proj(
    const float* __restrict__ x, const float* __restrict__ wn1,
    const float* __restrict__ ws1, const float* __restrict__ b1,
    const int* __restrict__ src, const int* __restrict__ dst,
    const int* __restrict__ pc, const int* __restrict__ starts,
    int* __restrict__ P, __half* __restrict__ xn1h,
    __half* __restrict__ y1h16) {
  __shared__ alignas(16) float xs[64 * 129];  // 33 KB; pfill aliases into it
  const int tid = threadIdx.x;
  if (blockIdx.x < ABLK) {
    int* base_s = (int*)xs;          // [NBKT] absolute base
    int* cur = (int*)xs + NBKT;      // [NBKT]
    for (int i = tid; i < NBKT; i += 256) {
      base_s[i] = starts[i] + pc[blockIdx.x * NBKT + i];
      cur[i] = 0;
    }
    __syncthreads();
    const int e0 = blockIdx.x * EPB;
    for (int e = e0 + tid; e < e0 + EPB; e += 256) {
      int d = dst[e], s = src[e];
      int b = d >> 8;
      int off = atomicAdd(&cur[b], 1);
      P[base_s[b] + off] = ((d & 255) << 17) | s;
    }
    return;
  }
  // ---- proj1 role ----
  const int node0 = (blockIdx.x - ABLK) * 64;
  for (int i = tid; i < 64 * 32; i += 256) {
    int r = i >> 5, cv = i & 31;
    int n = node0 + r;
    float4 v = make_float4(0.f, 0.f, 0.f, 0.f);
    if (n < N_NODES) v = ((const float4*)x)[(size_t)n * 32 + cv];
    float* dp = &xs[r * 129 + cv * 4];
    dp[0] = v.x; dp[1] = v.y; dp[2] = v.z; dp[3] = v.w;
  }
  __syncthreads();

  const int wave = __builtin_amdgcn_readfirstlane(tid >> 6);
  const int lane = tid & 63;
  const int n = node0 + lane;
  const float* wmat = (wave < 2) ? wn1 : ws1;
  const int c0 = (wave & 1) * 8;

  float acc[8] = {0.f, 0.f, 0.f, 0.f, 0.f, 0.f, 0.f, 0.f};
  const float* xrow = &xs[lane * 129];
#pragma unroll 8
  for (int k = 0; k < F; ++k) {
    float xv = xrow[k];
    const float* wr = wmat + k * H + c0;
#pragma unroll
    for (int j = 0; j < 8; ++j) acc[j] += xv * wr[j];
  }
  if (n < N_NODES) {
    union { ushort u[8]; uint4 v; } pk;
    if (wave < 2) {
#pragma unroll
      for (int j = 0; j < 8; ++j) pk.u[j] = pkh(acc[j]);
      *(uint4*)&xn1h[n * H + c0] = pk.v;
    } else {
#pragma unroll
      for (int j = 0; j < 8; ++j) pk.u[j] = pkh(acc[j] + b1[c0 + j]);
      *(uint4*)&y1h16[n * H + c0] = pk.v;
    }
  }
}

// ---- scatter one fp16 row (2 x uint4 = 16 halves) into LDS accumulator -----
#define SCATTER_ROW(ag, a, b)                                          \
  atomicAdd(&ag[0], cvh((ushort)(a.x)));                               \
  atomicAdd(&ag[1], cvh((ushort)(a.x >> 16)));                         \
  atomicAdd(&ag[2], cvh((ushort)(a.y)));                               \
  atomicAdd(&ag[3], cvh((ushort)(a.y >> 16)));                         \
  atomicAdd(&ag[4], cvh((ushort)(a.z)));                               \
  atomicAdd(&ag[5], cvh((ushort)(a.z >> 16)));                         \
  atomicAdd(&ag[6], cvh((ushort)(a.w)));                               \
  atomicAdd(&ag[7], cvh((ushort)(a.w >> 16)));                         \
  atomicAdd(&ag[8], cvh((ushort)(b.x)));                               \
  atomicAdd(&ag[9], cvh((ushort)(b.x >> 16)));                         \
  atomicAdd(&ag[10], cvh((ushort)(b.y)));                              \
  atomicAdd(&ag[11], cvh((ushort)(b.y >> 16)));                        \
  atomicAdd(&ag[12], cvh((ushort)(b.z)));                              \
  atomicAdd(&ag[13], cvh((ushort)(b.z >> 16)));                        \
  atomicAdd(&ag[14], cvh((ushort)(b.w)));                              \
  atomicAdd(&ag[15], cvh((ushort)(b.w >> 16)));

// ------- layer-1 aggregation: per-bucket stream-scatter ---------------------
// Block = bucket (256 nodes). Stream the bucket's pairs coalesced; scatter
// rows into LDS agg via ds_add_f32. No sort, no per-node pull chains.
// Epilogue: h16[n] = relu(y1[n] + agg[n]/deg[n]).
__global__ __launch_bounds__(256) void k_agg1(
    const int* __restrict__ starts, const int* __restrict__ counts,
    const int* __restrict__ P, const __half* __restrict__ xn1h,
    const __half* __restrict__ y1h16, __half* __restrict__ h16) {
  __shared__ float agg[256][17];
  __shared__ int deg[256];
  const int t = blockIdx.x, tid = threadIdx.x;
  for (int i = tid; i < 256 * 17; i += 256) ((float*)agg)[i] = 0.f;
  deg[tid] = 0;
  __syncthreads();
  const int st = starts[t], en = st + counts[t];
  const uint4* xr = (const uint4*)xn1h;  // 2 uint4 per 32B row
  for (int e = st + tid; e < en; e += 256) {
    int pv = P[e];
    int nl = pv >> 17, s = pv & 0x1FFFF;
    uint4 a = xr[s * 2], b = xr[s * 2 + 1];
    atomicAdd(&deg[nl], 1);
    float* ag = agg[nl];
    SCATTER_ROW(ag, a, b)
  }
  __syncthreads();
  const int n = t * 256 + tid;
  if (n < N_NODES) {
    const float rd = 1.0f / fmaxf((float)deg[tid], 1.0f);
    uint4 ya = ((const uint4*)y1h16)[n * 2];
    uint4 yb = ((const uint4*)y1h16)[n * 2 + 1];
    const float* ag = agg[tid];
    float o[16];
    o[0] = fmaxf(cvh((ushort)(ya.x)) + ag[0] * rd, 0.f);
    o[1] = fmaxf(cvh((ushort)(ya.x >> 16)) + ag[1] * rd, 0.f);
    o[2] = fmaxf(cvh((ushort)(ya.y)) + ag[2] * rd, 0.f);
    o[3] = fmaxf(cvh((ushort)(ya.y >> 16)) + ag[3] * rd, 0.f);
    o[4] = fmaxf(cvh((ushort)(ya.z)) + ag[4] * rd, 0.f);
    o[5] = fmaxf(cvh((ushort)(ya.z >> 16)) + ag[5] * rd, 0.f);
    o[6] = fmaxf(cvh((ushort)(ya.w)) + ag[6] * rd, 0.f);
    o[7] = fmaxf(cvh((ushort)(ya.w >> 16)) + ag[7] * rd, 0.f);
    o[8] = fmaxf(cvh((ushort)(yb.x)) + ag[8] * rd, 0.f);
    o[9] = fmaxf(cvh((ushort)(yb.x >> 16)) + ag[9] * rd, 0.f);
    o[10] = fmaxf(cvh((ushort)(yb.y)) + ag[10] * rd, 0.f);
    o[11] = fmaxf(cvh((ushort)(yb.y >> 16)) + ag[11] * rd, 0.f);
    o[12] = fmaxf(cvh((ushort)(yb.z)) + ag[12] * rd, 0.f);
    o[13] = fmaxf(cvh((ushort)(yb.z >> 16)) + ag[13] * rd, 0.f);
    o[14] = fmaxf(cvh((ushort)(yb.w)) + ag[14] * rd, 0.f);
    o[15] = fmaxf(cvh((ushort)(yb.w >> 16)) + ag[15] * rd, 0.f);
    uint4 wa, wb;
    wa.x = pk2(o[0], o[1]);  wa.y = pk2(o[2], o[3]);
    wa.z = pk2(o[4], o[5]);  wa.w = pk2(o[6], o[7]);
    wb.x = pk2(o[8], o[9]);  wb.y = pk2(o[10], o[11]);
    wb.z = pk2(o[12], o[13]); wb.w = pk2(o[14], o[15]);
    ((uint4*)h16)[n * 2] = wa;
    ((uint4*)h16)[n * 2 + 1] = wb;
  }
}

// ------- layer-2 aggregation + output GEMM ----------------------------------
// Same stream-scatter with h16; epilogue: thread=node computes all 40 output
// cols in registers (weights wave-uniform s_loads), coalesced float4 stores.
__global__ __launch_bounds__(256) void k_agg2(
    const int* __restrict__ starts, const int* __restrict__ counts,
    const int* __restrict__ P, const __half* __restrict__ h16,
    const float* __restrict__ wn2, const float* __restrict__ ws2,
    const float* __restrict__ b2, float* __restrict__ out) {
  __shared__ float agg[256][17];
  __shared__ int deg[256];
  const int t = blockIdx.x, tid = threadIdx.x;
  for (int i = tid; i < 256 * 17; i += 256) ((float*)agg)[i] = 0.f;
  deg[tid] = 0;
  __syncthreads();
  const int st = starts[t], en = st + counts[t];
  const uint4* hr = (const uint4*)h16;
  for (int e = st + tid; e < en; e += 256) {
    int pv = P[e];
    int nl = pv >> 17, s = pv & 0x1FFFF;
    uint4 a = hr[s * 2], b = hr[s * 2 + 1];
    atomicAdd(&deg[nl], 1);
    float* ag = agg[nl];
    SCATTER_ROW(ag, a, b)
  }
  __syncthreads();
  const int n = t * 256 + tid;
  if (n >= N_NODES) return;
  const float rd = 1.0f / fmaxf((float)deg[tid], 1.0f);
  uint4 ha = hr[n * 2], hb = hr[n * 2 + 1];
  float hv[16];
  hv[0] = cvh((ushort)(ha.x));  hv[1] = cvh((ushort)(ha.x >> 16));
  hv[2] = cvh((ushort)(ha.y));  hv[3] = cvh((ushort)(ha.y >> 16));
  hv[4] = cvh((ushort)(ha.z));  hv[5] = cvh((ushort)(ha.z >> 16));
  hv[6] = cvh((ushort)(ha.w));  hv[7] = cvh((ushort)(ha.w >> 16));
  hv[8] = cvh((ushort)(hb.x));  hv[9] = cvh((ushort)(hb.x >> 16));
  hv[10] = cvh((ushort)(hb.y)); hv[11] = cvh((ushort)(hb.y >> 16));
  hv[12] = cvh((ushort)(hb.z)); hv[13] = cvh((ushort)(hb.z >> 16));
  hv[14] = cvh((ushort)(hb.w)); hv[15] = cvh((ushort)(hb.w >> 16));
  float mv[16];
#pragma unroll
  for (int k = 0; k < H; ++k) mv[k] = agg[tid][k] * rd;
  float acc[C];
#pragma unroll
  for (int c = 0; c < C; ++c) acc[c] = b2[c];
#pragma unroll
  for (int k = 0; k < H; ++k) {
    float a = hv[k];
    const float* wr = ws2 + k * C;  // wave-uniform -> s_load
#pragma unroll
    for (int c = 0; c < C; ++c) acc[c] += a * wr[c];
  }
#pragma unroll
  for (int k = 0; k < H; ++k) {
    float a = mv[k];
    const float* wr = wn2 + k * C;  // wave-uniform -> s_load
#pragma unroll
    for (int c = 0; c < C; ++c) acc[c] += a * wr[c];
  }
  float* orow = &out[(size_t)n * C];
#pragma unroll
  for (int q = 0; q < C / 4; ++q)
    *(float4*)&orow[q * 4] =
        make_float4(acc[q * 4], acc[q * 4 + 1], acc[q * 4 + 2], acc[q * 4 + 3]);
}

extern "C" void kernel_launch(void* const* d_in, const int* in_sizes, int n_in,
                              void* d_out, int out_size, void* d_ws,
                              size_t ws_size, hipStream_t stream) {
  const float* x = (const float*)d_in[0];
  const int* src = (const int*)d_in[1];
  const int* dst = (const int*)d_in[2];
  const float* wn1 = (const float*)d_in[3];
  const float* ws1 = (const float*)d_in[4];
  const float* b1 = (const float*)d_in[5];
  const float* wn2 = (const float*)d_in[6];
  const float* ws2 = (const float*)d_in[7];
  const float* b2 = (const float*)d_in[8];
  float* out = (float*)d_out;

  // xn1 (fp16, 3.2MB) lives in d_out (consumed by k_agg1 before k_agg2
  // writes d_out).
  __half* xn1h = (__half*)out;

  // ws layout (float offsets), 13.2 MB total (same byte footprint):
  //   [100000, 100391)         starts (int)
  //   [100391, 100782)         counts (int)
  //   [102400, 102400+E)       P: packed pairs (int)
  //   [102400+E, +NH/2)        y1 (fp16, NH halves)
  //   [102400+E+NH/2, +NH/2)   h  (fp16, NH halves)
  //   pc (int[256*391] = 400 KB) OVERLAYS the h region (dead after fill).
  float* wsp = (float*)d_ws;
  int* starts = (int*)wsp + 100000;
  int* counts = (int*)wsp + 100391;
  int* P = (int*)(wsp + 102400);
  __half* y1h16 = (__half*)(wsp + 102400 + N_EDGES);
  __half* h16 = (__half*)(wsp + 102400 + N_EDGES + NH / 2);
  int* pc = (int*)(wsp + 102400 + N_EDGES + NH / 2);  // overlay on h16

  k_pcount<<<ABLK, 256, 0, stream>>>(dst, pc);
  k_pscanA<<<NBKT, 256, 0, stream>>>(pc, counts);
  k_pscanB<<<1, 512, 0, stream>>>(counts, starts);
  k_fill_proj<<<ABLK + PROJB, 256, 0, stream>>>(x, wn1, ws1, b1, src, dst, pc,
                                                starts, P, xn1h, y1h16);
  k_agg1<<<NBKT, 256, 0, stream>>>(starts, counts, P, xn1h, y1h16, h16);
  k_agg2<<<NBKT, 256, 0, stream>>>(starts, counts, P, h16, wn2, ws2, b2, out);
}

// Round 11
// 206.257 us; speedup vs baseline: 2.3763x; 2.3763x over previous
//
#include <hip/hip_runtime.h>
#include <hip/hip_fp16.h>

#define N_NODES 100000
#define N_EDGES 1600000
#define F 128
#define H 16
#define C 40
#define NH (N_NODES * H)
#define NBKT 391   // buckets of 256 nodes: ceil(100000/256)
#define ABLK 256   // partition blocks
#define EPB 6250   // edges per partition block (256*6250 = 1.6M exact)
#define CAP 6144   // per-bucket LDS capacity (mean 4096, ~32 sigma headroom)
#define PROJB 1563 // proj1 blocks: ceil(100000/64)

__device__ __forceinline__ float cvh(ushort u) {
  return __half2float(__ushort_as_half(u));
}
__device__ __forceinline__ ushort pkh(float f) {
  return __half_as_ushort(__float2half(f));
}
__device__ __forceinline__ unsigned pk2(float lo, float hi) {
  return (unsigned)pkh(lo) | ((unsigned)pkh(hi) << 16);
}

// ---------------- CSR build 1: per-block bucket rows (plain stores) ---------
__global__ __launch_bounds__(256) void k_pcount(const int* __restrict__ dst,
                                                int* __restrict__ pc) {
  __shared__ int cnt[NBKT];
  for (int i = threadIdx.x; i < NBKT; i += 256) cnt[i] = 0;
  __syncthreads();
  const int e0 = blockIdx.x * EPB;
  for (int e = e0 + threadIdx.x; e < e0 + EPB; e += 256)
    atomicAdd(&cnt[dst[e] >> 8], 1);
  __syncthreads();
  for (int i = threadIdx.x; i < NBKT; i += 256)
    pc[blockIdx.x * NBKT + i] = cnt[i];
}

// ---------------- CSR build 2a: per-bucket column scan (391 parallel blocks)
__global__ __launch_bounds__(256) void k_pscanA(int* __restrict__ pc,
                                                int* __restrict__ counts) {
  __shared__ int ls[256];
  const int t = blockIdx.x, tid = threadIdx.x;
  int v = pc[tid * NBKT + t];
  ls[tid] = v;
  __syncthreads();
  for (int off = 1; off < 256; off <<= 1) {
    int a = (tid >= off) ? ls[tid - off] : 0;
    __syncthreads();
    ls[tid] += a;
    __syncthreads();
  }
  pc[tid * NBKT + t] = ls[tid] - v;  // local exclusive base
  if (tid == 255) counts[t] = ls[255];
}

// ---------------- CSR build 2b: scan 391 bucket totals -> global starts -----
__global__ __launch_bounds__(512) void k_pscanB(const int* __restrict__ counts,
                                                int* __restrict__ starts) {
  __shared__ int ls[512];
  const int tid = threadIdx.x;
  int v = (tid < NBKT) ? counts[tid] : 0;
  ls[tid] = v;
  __syncthreads();
  for (int off = 1; off < 512; off <<= 1) {
    int a = (tid >= off) ? ls[tid - off] : 0;
    __syncthreads();
    ls[tid] += a;
    __syncthreads();
  }
  if (tid < NBKT) starts[tid] = ls[tid] - v;  // exclusive
}

// ---------------- CSR fill (blocks 0..255) fused with proj1 (rest) ----------
// pair = (dlocal<<17) | src  (dlocal<256 -> 8 bits; src<100000 -> 17 bits)
__global__ __launch_bounds__(256) void k_fill_proj(
    const float* __restrict__ x, const float* __restrict__ wn1,
    const float* __restrict__ ws1, const float* __restrict__ b1,
    const int* __restrict__ src, const int* __restrict__ dst,
    const int* __restrict__ pc, const int* __restrict__ starts,
    int* __restrict__ P, __half* __restrict__ xn1h,
    __half* __restrict__ y1h16) {
  __shared__ alignas(16) float xs[64 * 129];  // 33 KB; pfill aliases into it
  const int tid = threadIdx.x;
  if (blockIdx.x < ABLK) {
    int* base_s = (int*)xs;          // [NBKT] absolute base
    int* cur = (int*)xs + NBKT;      // [NBKT]
    for (int i = tid; i < NBKT; i += 256) {
      base_s[i] = starts[i] + pc[blockIdx.x * NBKT + i];
      cur[i] = 0;
    }
    __syncthreads();
    const int e0 = blockIdx.x * EPB;
    for (int e = e0 + tid; e < e0 + EPB; e += 256) {
      int d = dst[e], s = src[e];
      int b = d >> 8;
      int off = atomicAdd(&cur[b], 1);
      P[base_s[b] + off] = ((d & 255) << 17) | s;
    }
    return;
  }
  // ---- proj1 role ----
  const int node0 = (blockIdx.x - ABLK) * 64;
  for (int i = tid; i < 64 * 32; i += 256) {
    int r = i >> 5, cv = i & 31;
    int n = node0 + r;
    float4 v = make_float4(0.f, 0.f, 0.f, 0.f);
    if (n < N_NODES) v = ((const float4*)x)[(size_t)n * 32 + cv];
    float* dp = &xs[r * 129 + cv * 4];
    dp[0] = v.x; dp[1] = v.y; dp[2] = v.z; dp[3] = v.w;
  }
  __syncthreads();

  const int wave = __builtin_amdgcn_readfirstlane(tid >> 6);
  const int lane = tid & 63;
  const int n = node0 + lane;
  const float* wmat = (wave < 2) ? wn1 : ws1;
  const int c0 = (wave & 1) * 8;

  float acc[8] = {0.f, 0.f, 0.f, 0.f, 0.f, 0.f, 0.f, 0.f};
  const float* xrow = &xs[lane * 129];
#pragma unroll 8
  for (int k = 0; k < F; ++k) {
    float xv = xrow[k];
    const float* wr = wmat + k * H + c0;
#pragma unroll
    for (int j = 0; j < 8; ++j) acc[j] += xv * wr[j];
  }
  if (n < N_NODES) {
    union { ushort u[8]; uint4 v; } pk;
    if (wave < 2) {
#pragma unroll
      for (int j = 0; j < 8; ++j) pk.u[j] = pkh(acc[j]);
      *(uint4*)&xn1h[n * H + c0] = pk.v;
    } else {
#pragma unroll
      for (int j = 0; j < 8; ++j) pk.u[j] = pkh(acc[j] + b1[c0 + j]);
      *(uint4*)&y1h16[n * H + c0] = pk.v;
    }
  }
}

// ---- accumulate one 32B fp16 row (2 x uint4) into float acc[16] ------------
#define ACC_ROW(a, b)                                                   \
  acc[0] += cvh((ushort)(a.x)); acc[1] += cvh((ushort)(a.x >> 16));     \
  acc[2] += cvh((ushort)(a.y)); acc[3] += cvh((ushort)(a.y >> 16));     \
  acc[4] += cvh((ushort)(a.z)); acc[5] += cvh((ushort)(a.z >> 16));     \
  acc[6] += cvh((ushort)(a.w)); acc[7] += cvh((ushort)(a.w >> 16));     \
  acc[8] += cvh((ushort)(b.x)); acc[9] += cvh((ushort)(b.x >> 16));     \
  acc[10] += cvh((ushort)(b.y)); acc[11] += cvh((ushort)(b.y >> 16));   \
  acc[12] += cvh((ushort)(b.z)); acc[13] += cvh((ushort)(b.z >> 16));   \
  acc[14] += cvh((ushort)(b.w)); acc[15] += cvh((ushort)(b.w >> 16));

// ------- bucket sort + layer-1 gather fused (replaces k_bcsr + k_gather1) ---
// Block = bucket (256 nodes), 512 threads.
// Sort phase (bcsr logic): LDS hist/scan/scatter of packed pairs; write sorted
// P + A end-offsets for k_gout. Gather phase: 2 threads/node pull directly
// from the LDS-resident sorted src list (no global srclist round-trip),
// ILP-4 full-row loads, f32 acc, 1x shfl_xor merge; h16 = relu(y1 + mean).
__global__ __launch_bounds__(512) void k_gsort1(
    const int* __restrict__ starts, const int* __restrict__ counts,
    int* __restrict__ P, int* __restrict__ A,
    const __half* __restrict__ xn1h, const __half* __restrict__ y1h16,
    __half* __restrict__ h16) {
  __shared__ int pbuf[CAP];
  __shared__ int sbuf[CAP];
  __shared__ int h[256];
  __shared__ int hstart[256];
  __shared__ int cur[256];
  const int t = blockIdx.x, tid = threadIdx.x;
  const int st = starts[t];
  int cnt = counts[t];
  if (cnt > CAP) cnt = CAP;  // ~impossible; guards LDS
  for (int i = tid; i < cnt; i += 512) pbuf[i] = P[st + i];
  if (tid < 256) h[tid] = 0;
  __syncthreads();
  for (int i = tid; i < cnt; i += 512) atomicAdd(&h[pbuf[i] >> 17], 1);
  __syncthreads();
  int v = (tid < 256) ? h[tid] : 0;
  for (int off = 1; off < 256; off <<= 1) {
    int a = (tid < 256 && tid >= off) ? h[tid - off] : 0;
    __syncthreads();
    if (tid < 256) h[tid] += a;
    __syncthreads();
  }
  if (tid < 256) {
    int incl = h[tid];
    hstart[tid] = incl - v;
    cur[tid] = incl - v;
    int node = t * 256 + tid;
    if (node < N_NODES) A[node] = st + incl;
  }
  __syncthreads();
  for (int i = tid; i < cnt; i += 512) {
    int pv = pbuf[i];
    int nl = pv >> 17;
    int p = atomicAdd(&cur[nl], 1);
    sbuf[p] = pv & 0x1FFFF;
  }
  __syncthreads();
  // write sorted srclist back for k_gout (coalesced)
  for (int i = tid; i < cnt; i += 512) P[st + i] = sbuf[i];

  // ---- gather phase: 2 threads per node, edges from LDS ----
  const int nl = tid >> 1, s = tid & 1;
  const int n = t * 256 + nl;
  if (n >= N_NODES) return;  // no further barriers
  const int lo = hstart[nl], hi = cur[nl];  // cur[nl] == end after scatter
  const uint4* xr = (const uint4*)xn1h;  // 2 uint4 per 32B row
  float acc[16];
#pragma unroll
  for (int i = 0; i < 16; ++i) acc[i] = 0.f;
  int e = lo + s;
  for (; e + 6 < hi; e += 8) {  // 4 edges/batch, 8 lines in flight
    int i0 = sbuf[e], i1 = sbuf[e + 2], i2 = sbuf[e + 4], i3 = sbuf[e + 6];
    uint4 a0 = xr[i0 * 2], b0 = xr[i0 * 2 + 1];
    uint4 a1 = xr[i1 * 2], b1 = xr[i1 * 2 + 1];
    uint4 a2 = xr[i2 * 2], b2 = xr[i2 * 2 + 1];
    uint4 a3 = xr[i3 * 2], b3 = xr[i3 * 2 + 1];
    ACC_ROW(a0, b0) ACC_ROW(a1, b1) ACC_ROW(a2, b2) ACC_ROW(a3, b3)
  }
  for (; e < hi; e += 2) {
    int i0 = sbuf[e];
    uint4 a0 = xr[i0 * 2], b0 = xr[i0 * 2 + 1];
    ACC_ROW(a0, b0)
  }
#pragma unroll
  for (int i = 0; i < 16; ++i) acc[i] += __shfl_xor(acc[i], 1);
  if (s == 0) {
    const float rd = 1.0f / fmaxf((float)(hi - lo), 1.0f);
    uint4 ya = ((const uint4*)y1h16)[n * 2];
    uint4 yb = ((const uint4*)y1h16)[n * 2 + 1];
    float o[16];
    o[0] = fmaxf(cvh((ushort)(ya.x)) + acc[0] * rd, 0.f);
    o[1] = fmaxf(cvh((ushort)(ya.x >> 16)) + acc[1] * rd, 0.f);
    o[2] = fmaxf(cvh((ushort)(ya.y)) + acc[2] * rd, 0.f);
    o[3] = fmaxf(cvh((ushort)(ya.y >> 16)) + acc[3] * rd, 0.f);
    o[4] = fmaxf(cvh((ushort)(ya.z)) + acc[4] * rd, 0.f);
    o[5] = fmaxf(cvh((ushort)(ya.z >> 16)) + acc[5] * rd, 0.f);
    o[6] = fmaxf(cvh((ushort)(ya.w)) + acc[6] * rd, 0.f);
    o[7] = fmaxf(cvh((ushort)(ya.w >> 16)) + acc[7] * rd, 0.f);
    o[8] = fmaxf(cvh((ushort)(yb.x)) + acc[8] * rd, 0.f);
    o[9] = fmaxf(cvh((ushort)(yb.x >> 16)) + acc[9] * rd, 0.f);
    o[10] = fmaxf(cvh((ushort)(yb.y)) + acc[10] * rd, 0.f);
    o[11] = fmaxf(cvh((ushort)(yb.y >> 16)) + acc[11] * rd, 0.f);
    o[12] = fmaxf(cvh((ushort)(yb.z)) + acc[12] * rd, 0.f);
    o[13] = fmaxf(cvh((ushort)(yb.z >> 16)) + acc[13] * rd, 0.f);
    o[14] = fmaxf(cvh((ushort)(yb.w)) + acc[14] * rd, 0.f);
    o[15] = fmaxf(cvh((ushort)(yb.w >> 16)) + acc[15] * rd, 0.f);
    uint4 wa, wb;
    wa.x = pk2(o[0], o[1]);   wa.y = pk2(o[2], o[3]);
    wa.z = pk2(o[4], o[5]);   wa.w = pk2(o[6], o[7]);
    wb.x = pk2(o[8], o[9]);   wb.y = pk2(o[10], o[11]);
    wb.z = pk2(o[12], o[13]); wb.w = pk2(o[14], o[15]);
    ((uint4*)h16)[n * 2] = wa;
    ((uint4*)h16)[n * 2 + 1] = wb;
  }
}

// ---- edge-sum macro body (round-9 k_gout, unchanged) -----------------------
#define GATHER_QUAD(tab)                                                    \
  {                                                                         \
    int e = start + s;                                                      \
    for (; e + 14 < end; e += 16) {                                         \
      int i0 = srclist[e], i1 = srclist[e + 2], i2 = srclist[e + 4],        \
          i3 = srclist[e + 6], i4 = srclist[e + 8], i5 = srclist[e + 10],   \
          i6 = srclist[e + 12], i7 = srclist[e + 14];                       \
      ushort4 q0 = tab[i0 * 4 + g], q1 = tab[i1 * 4 + g];                   \
      ushort4 q2 = tab[i2 * 4 + g], q3 = tab[i3 * 4 + g];                   \
      ushort4 q4 = tab[i4 * 4 + g], q5 = tab[i5 * 4 + g];                   \
      ushort4 q6 = tab[i6 * 4 + g], q7 = tab[i7 * 4 + g];                   \
      ax += cvh(q0.x) + cvh(q1.x) + cvh(q2.x) + cvh(q3.x) + cvh(q4.x) +     \
            cvh(q5.x) + cvh(q6.x) + cvh(q7.x);                              \
      ay += cvh(q0.y) + cvh(q1.y) + cvh(q2.y) + cvh(q3.y) + cvh(q4.y) +     \
            cvh(q5.y) + cvh(q6.y) + cvh(q7.y);                              \
      az += cvh(q0.z) + cvh(q1.z) + cvh(q2.z) + cvh(q3.z) + cvh(q4.z) +     \
            cvh(q5.z) + cvh(q6.z) + cvh(q7.z);                              \
      aw += cvh(q0.w) + cvh(q1.w) + cvh(q2.w) + cvh(q3.w) + cvh(q4.w) +     \
            cvh(q5.w) + cvh(q6.w) + cvh(q7.w);                              \
    }                                                                       \
    for (; e + 6 < end; e += 8) {                                           \
      int i0 = srclist[e], i1 = srclist[e + 2], i2 = srclist[e + 4],        \
          i3 = srclist[e + 6];                                              \
      ushort4 q0 = tab[i0 * 4 + g], q1 = tab[i1 * 4 + g];                   \
      ushort4 q2 = tab[i2 * 4 + g], q3 = tab[i3 * 4 + g];                   \
      ax += cvh(q0.x) + cvh(q1.x) + cvh(q2.x) + cvh(q3.x);                  \
      ay += cvh(q0.y) + cvh(q1.y) + cvh(q2.y) + cvh(q3.y);                  \
      az += cvh(q0.z) + cvh(q1.z) + cvh(q2.z) + cvh(q3.z);                  \
      aw += cvh(q0.w) + cvh(q1.w) + cvh(q2.w) + cvh(q3.w);                  \
    }                                                                       \
    for (; e < end; e += 2) {                                               \
      ushort4 q = tab[srclist[e] * 4 + g];                                  \
      ax += cvh(q.x); ay += cvh(q.y); az += cvh(q.z); aw += cvh(q.w);       \
    }                                                                       \
  }

// ------- gather layer 2 fused with output GEMM (round-9 version) ------------
__global__ __launch_bounds__(512) void k_gout(
    const __half* __restrict__ h16, const int* __restrict__ A,
    const int* __restrict__ srclist, const float* __restrict__ wn,
    const float* __restrict__ wsf, const float* __restrict__ b,
    float* __restrict__ out) {
  __shared__ float hm[64][33];  // [node][0:16)=h, [16:32)=mean; pad 33
  const int tid = threadIdx.x;
  const int node0 = blockIdx.x * 64;
  const int nl = tid >> 3, g = tid & 3, s = (tid >> 2) & 1;
  const int n = node0 + nl;
  const ushort4* hr = (const ushort4*)h16;
  if (n < N_NODES) {
    const int end = A[n];
    const int start = n ? A[n - 1] : 0;
    float ax = 0.f, ay = 0.f, az = 0.f, aw = 0.f;
    GATHER_QUAD(hr)
    ax += __shfl_xor(ax, 4);
    ay += __shfl_xor(ay, 4);
    az += __shfl_xor(az, 4);
    aw += __shfl_xor(aw, 4);
    if (s == 0) {
      const float rd = 1.0f / fmaxf((float)(end - start), 1.0f);
      ushort4 qh = hr[n * 4 + g];
      float* hv = &hm[nl][g * 4];
      hv[0] = cvh(qh.x); hv[1] = cvh(qh.y);
      hv[2] = cvh(qh.z); hv[3] = cvh(qh.w);
      float* mv = &hm[nl][16 + g * 4];
      mv[0] = ax * rd; mv[1] = ay * rd; mv[2] = az * rd; mv[3] = aw * rd;
    }
  }
  __syncthreads();

  const int wv = tid >> 6;    // 0..7 -> 5-col group
  const int lane = tid & 63;  // local node
  const int on = node0 + lane;
  const int c0 = wv * 5;
  float acc[5];
#pragma unroll
  for (int j = 0; j < 5; ++j) acc[j] = b[c0 + j];
#pragma unroll
  for (int k = 0; k < H; ++k) {
    float hv = hm[lane][k];
    const float* wr = wsf + k * C + c0;  // wave-uniform -> s_load
#pragma unroll
    for (int j = 0; j < 5; ++j) acc[j] += hv * wr[j];
  }
#pragma unroll
  for (int k = 0; k < H; ++k) {
    float mv = hm[lane][16 + k];
    const float* wr = wn + k * C + c0;  // wave-uniform -> s_load
#pragma unroll
    for (int j = 0; j < 5; ++j) acc[j] += mv * wr[j];
  }
  if (on < N_NODES) {
#pragma unroll
    for (int j = 0; j < 5; ++j) out[on * C + c0 + j] = acc[j];
  }
}

extern "C" void kernel_launch(void* const* d_in, const int* in_sizes, int n_in,
                              void* d_out, int out_size, void* d_ws,
                              size_t ws_size, hipStream_t stream) {
  const float* x = (const float*)d_in[0];
  const int* src = (const int*)d_in[1];
  const int* dst = (const int*)d_in[2];
  const float* wn1 = (const float*)d_in[3];
  const float* ws1 = (const float*)d_in[4];
  const float* b1 = (const float*)d_in[5];
  const float* wn2 = (const float*)d_in[6];
  const float* ws2 = (const float*)d_in[7];
  const float* b2 = (const float*)d_in[8];
  float* out = (float*)d_out;

  // xn1 (fp16, 3.2MB) lives in d_out (consumed by k_gsort1 before k_gout
  // writes d_out).
  __half* xn1h = (__half*)out;

  // ws layout (float offsets), 13.2 MB total (same byte footprint):
  //   [0, 100000)              A: CSR end offsets (int)
  //   [100000, 100391)         starts (int)
  //   [100391, 100782)         counts (int)
  //   [102400, 102400+E)       P: packed pairs -> sorted srclist in place (int)
  //   [102400+E, +NH/2)        y1 (fp16, NH halves)
  //   [102400+E+NH/2, +NH/2)   h  (fp16, NH halves)
  //   pc (int[256*391] = 400 KB) OVERLAYS the h region (dead after fill).
  float* wsp = (float*)d_ws;
  int* A = (int*)wsp;
  int* starts = (int*)wsp + 100000;
  int* counts = (int*)wsp + 100391;
  int* P = (int*)(wsp + 102400);
  __half* y1h16 = (__half*)(wsp + 102400 + N_EDGES);
  __half* h16 = (__half*)(wsp + 102400 + N_EDGES + NH / 2);
  int* pc = (int*)(wsp + 102400 + N_EDGES + NH / 2);  // overlay on h16

  k_pcount<<<ABLK, 256, 0, stream>>>(dst, pc);
  k_pscanA<<<NBKT, 256, 0, stream>>>(pc, counts);
  k_pscanB<<<1, 512, 0, stream>>>(counts, starts);
  k_fill_proj<<<ABLK + PROJB, 256, 0, stream>>>(x, wn1, ws1, b1, src, dst, pc,
                                                starts, P, xn1h, y1h16);
  k_gsort1<<<NBKT, 512, 0, stream>>>(starts, counts, P, A, xn1h, y1h16, h16);
  k_gout<<<(N_NODES + 63) / 64, 512, 0, stream>>>(h16, A, P, wn2, ws2, b2,
                                                  out);
}

// Round 12
// 189.106 us; speedup vs baseline: 2.5918x; 1.0907x over previous
//
#include <hip/hip_runtime.h>
#include <hip/hip_fp16.h>

#define N_NODES 100000
#define N_EDGES 1600000
#define F 128
#define H 16
#define C 40
#define NH (N_NODES * H)
#define NBKT 391   // buckets of 256 nodes: ceil(100000/256)
#define ABLK 256   // partition blocks
#define EPB 6250   // edges per partition block (256*6250 = 1.6M exact)
#define CAP 6144   // per-bucket LDS capacity (mean 4096, ~32 sigma headroom)
#define PROJB 1563 // proj1 blocks: ceil(100000/64)
#define GCAP 3136  // per-half-bucket LDS capacity (mean 2048, ~24 sigma)
#define GBLK 782   // gout blocks: ceil(100000/128)

__device__ __forceinline__ float cvh(ushort u) {
  return __half2float(__ushort_as_half(u));
}
__device__ __forceinline__ ushort pkh(float f) {
  return __half_as_ushort(__float2half(f));
}
__device__ __forceinline__ unsigned pk2(float lo, float hi) {
  return (unsigned)pkh(lo) | ((unsigned)pkh(hi) << 16);
}

// ---------------- CSR build 1: per-block bucket rows (plain stores) ---------
__global__ __launch_bounds__(256) void k_pcount(const int* __restrict__ dst,
                                                int* __restrict__ pc) {
  __shared__ int cnt[NBKT];
  for (int i = threadIdx.x; i < NBKT; i += 256) cnt[i] = 0;
  __syncthreads();
  const int e0 = blockIdx.x * EPB;
  for (int e = e0 + threadIdx.x; e < e0 + EPB; e += 256)
    atomicAdd(&cnt[dst[e] >> 8], 1);
  __syncthreads();
  for (int i = threadIdx.x; i < NBKT; i += 256)
    pc[blockIdx.x * NBKT + i] = cnt[i];
}

// ---------------- CSR build 2a: per-bucket column scan (391 parallel blocks)
__global__ __launch_bounds__(256) void k_pscanA(int* __restrict__ pc,
                                                int* __restrict__ counts) {
  __shared__ int ls[256];
  const int t = blockIdx.x, tid = threadIdx.x;
  int v = pc[tid * NBKT + t];
  ls[tid] = v;
  __syncthreads();
  for (int off = 1; off < 256; off <<= 1) {
    int a = (tid >= off) ? ls[tid - off] : 0;
    __syncthreads();
    ls[tid] += a;
    __syncthreads();
  }
  pc[tid * NBKT + t] = ls[tid] - v;  // local exclusive base
  if (tid == 255) counts[t] = ls[255];
}

// ---------------- CSR build 2b: scan 391 bucket totals -> global starts -----
__global__ __launch_bounds__(512) void k_pscanB(const int* __restrict__ counts,
                                                int* __restrict__ starts) {
  __shared__ int ls[512];
  const int tid = threadIdx.x;
  int v = (tid < NBKT) ? counts[tid] : 0;
  ls[tid] = v;
  __syncthreads();
  for (int off = 1; off < 512; off <<= 1) {
    int a = (tid >= off) ? ls[tid - off] : 0;
    __syncthreads();
    ls[tid] += a;
    __syncthreads();
  }
  if (tid < NBKT) starts[tid] = ls[tid] - v;  // exclusive
}

// ---------------- CSR fill (blocks 0..255) fused with proj1 (rest) ----------
// pair = (dlocal<<17) | src  (dlocal<256 -> 8 bits; src<100000 -> 17 bits)
__global__ __launch_bounds__(256) void k_fill_proj(
    const float* __restrict__ x, const float* __restrict__ wn1,
    const float* __restrict__ ws1, const float* __restrict__ b1,
    const int* __restrict__ src, const int* __restrict__ dst,
    const int* __restrict__ pc, const int* __restrict__ starts,
    int* __restrict__ P, __half* __restrict__ xn1h,
    __half* __restrict__ y1h16) {
  __shared__ alignas(16) float xs[64 * 129];  // 33 KB; pfill aliases into it
  const int tid = threadIdx.x;
  if (blockIdx.x < ABLK) {
    int* base_s = (int*)xs;          // [NBKT] absolute base
    int* cur = (int*)xs + NBKT;      // [NBKT]
    for (int i = tid; i < NBKT; i += 256) {
      base_s[i] = starts[i] + pc[blockIdx.x * NBKT + i];
      cur[i] = 0;
    }
    __syncthreads();
    const int e0 = blockIdx.x * EPB;
    for (int e = e0 + tid; e < e0 + EPB; e += 256) {
      int d = dst[e], s = src[e];
      int b = d >> 8;
      int off = atomicAdd(&cur[b], 1);
      P[base_s[b] + off] = ((d & 255) << 17) | s;
    }
    return;
  }
  // ---- proj1 role ----
  const int node0 = (blockIdx.x - ABLK) * 64;
  for (int i = tid; i < 64 * 32; i += 256) {
    int r = i >> 5, cv = i & 31;
    int n = node0 + r;
    float4 v = make_float4(0.f, 0.f, 0.f, 0.f);
    if (n < N_NODES) v = ((const float4*)x)[(size_t)n * 32 + cv];
    float* dp = &xs[r * 129 + cv * 4];
    dp[0] = v.x; dp[1] = v.y; dp[2] = v.z; dp[3] = v.w;
  }
  __syncthreads();

  const int wave = __builtin_amdgcn_readfirstlane(tid >> 6);
  const int lane = tid & 63;
  const int n = node0 + lane;
  const float* wmat = (wave < 2) ? wn1 : ws1;
  const int c0 = (wave & 1) * 8;

  float acc[8] = {0.f, 0.f, 0.f, 0.f, 0.f, 0.f, 0.f, 0.f};
  const float* xrow = &xs[lane * 129];
#pragma unroll 8
  for (int k = 0; k < F; ++k) {
    float xv = xrow[k];
    const float* wr = wmat + k * H + c0;
#pragma unroll
    for (int j = 0; j < 8; ++j) acc[j] += xv * wr[j];
  }
  if (n < N_NODES) {
    union { ushort u[8]; uint4 v; } pk;
    if (wave < 2) {
#pragma unroll
      for (int j = 0; j < 8; ++j) pk.u[j] = pkh(acc[j]);
      *(uint4*)&xn1h[n * H + c0] = pk.v;
    } else {
#pragma unroll
      for (int j = 0; j < 8; ++j) pk.u[j] = pkh(acc[j] + b1[c0 + j]);
      *(uint4*)&y1h16[n * H + c0] = pk.v;
    }
  }
}

// ---- accumulate one 32B fp16 row (2 x uint4) into float acc[16] ------------
#define ACC_ROW(a, b)                                                   \
  acc[0] += cvh((ushort)(a.x)); acc[1] += cvh((ushort)(a.x >> 16));     \
  acc[2] += cvh((ushort)(a.y)); acc[3] += cvh((ushort)(a.y >> 16));     \
  acc[4] += cvh((ushort)(a.z)); acc[5] += cvh((ushort)(a.z >> 16));     \
  acc[6] += cvh((ushort)(a.w)); acc[7] += cvh((ushort)(a.w >> 16));     \
  acc[8] += cvh((ushort)(b.x)); acc[9] += cvh((ushort)(b.x >> 16));     \
  acc[10] += cvh((ushort)(b.y)); acc[11] += cvh((ushort)(b.y >> 16));   \
  acc[12] += cvh((ushort)(b.z)); acc[13] += cvh((ushort)(b.z >> 16));   \
  acc[14] += cvh((ushort)(b.w)); acc[15] += cvh((ushort)(b.w >> 16));

// ------- bucket sort + layer-1 gather fused ---------------------------------
__global__ __launch_bounds__(512) void k_gsort1(
    const int* __restrict__ starts, const int* __restrict__ counts,
    int* __restrict__ P, int* __restrict__ A,
    const __half* __restrict__ xn1h, const __half* __restrict__ y1h16,
    __half* __restrict__ h16) {
  __shared__ int pbuf[CAP];
  __shared__ int sbuf[CAP];
  __shared__ int h[256];
  __shared__ int hstart[256];
  __shared__ int cur[256];
  const int t = blockIdx.x, tid = threadIdx.x;
  const int st = starts[t];
  int cnt = counts[t];
  if (cnt > CAP) cnt = CAP;  // ~impossible; guards LDS
  for (int i = tid; i < cnt; i += 512) pbuf[i] = P[st + i];
  if (tid < 256) h[tid] = 0;
  __syncthreads();
  for (int i = tid; i < cnt; i += 512) atomicAdd(&h[pbuf[i] >> 17], 1);
  __syncthreads();
  int v = (tid < 256) ? h[tid] : 0;
  for (int off = 1; off < 256; off <<= 1) {
    int a = (tid < 256 && tid >= off) ? h[tid - off] : 0;
    __syncthreads();
    if (tid < 256) h[tid] += a;
    __syncthreads();
  }
  if (tid < 256) {
    int incl = h[tid];
    hstart[tid] = incl - v;
    cur[tid] = incl - v;
    int node = t * 256 + tid;
    if (node < N_NODES) A[node] = st + incl;
  }
  __syncthreads();
  for (int i = tid; i < cnt; i += 512) {
    int pv = pbuf[i];
    int nl = pv >> 17;
    int p = atomicAdd(&cur[nl], 1);
    sbuf[p] = pv & 0x1FFFF;
  }
  __syncthreads();
  // write sorted srclist back for k_gout2 (coalesced)
  for (int i = tid; i < cnt; i += 512) P[st + i] = sbuf[i];

  // ---- gather phase: 2 threads per node, edges from LDS ----
  const int nl = tid >> 1, s = tid & 1;
  const int n = t * 256 + nl;
  if (n >= N_NODES) return;  // no further barriers
  const int lo = hstart[nl], hi = cur[nl];  // cur[nl] == end after scatter
  const uint4* xr = (const uint4*)xn1h;  // 2 uint4 per 32B row
  float acc[16];
#pragma unroll
  for (int i = 0; i < 16; ++i) acc[i] = 0.f;
  int e = lo + s;
  for (; e + 6 < hi; e += 8) {  // 4 edges/batch, 8 lines in flight
    int i0 = sbuf[e], i1 = sbuf[e + 2], i2 = sbuf[e + 4], i3 = sbuf[e + 6];
    uint4 a0 = xr[i0 * 2], b0 = xr[i0 * 2 + 1];
    uint4 a1 = xr[i1 * 2], b1 = xr[i1 * 2 + 1];
    uint4 a2 = xr[i2 * 2], b2 = xr[i2 * 2 + 1];
    uint4 a3 = xr[i3 * 2], b3 = xr[i3 * 2 + 1];
    ACC_ROW(a0, b0) ACC_ROW(a1, b1) ACC_ROW(a2, b2) ACC_ROW(a3, b3)
  }
  for (; e < hi; e += 2) {
    int i0 = sbuf[e];
    uint4 a0 = xr[i0 * 2], b0 = xr[i0 * 2 + 1];
    ACC_ROW(a0, b0)
  }
#pragma unroll
  for (int i = 0; i < 16; ++i) acc[i] += __shfl_xor(acc[i], 1);
  if (s == 0) {
    const float rd = 1.0f / fmaxf((float)(hi - lo), 1.0f);
    uint4 ya = ((const uint4*)y1h16)[n * 2];
    uint4 yb = ((const uint4*)y1h16)[n * 2 + 1];
    float o[16];
    o[0] = fmaxf(cvh((ushort)(ya.x)) + acc[0] * rd, 0.f);
    o[1] = fmaxf(cvh((ushort)(ya.x >> 16)) + acc[1] * rd, 0.f);
    o[2] = fmaxf(cvh((ushort)(ya.y)) + acc[2] * rd, 0.f);
    o[3] = fmaxf(cvh((ushort)(ya.y >> 16)) + acc[3] * rd, 0.f);
    o[4] = fmaxf(cvh((ushort)(ya.z)) + acc[4] * rd, 0.f);
    o[5] = fmaxf(cvh((ushort)(ya.z >> 16)) + acc[5] * rd, 0.f);
    o[6] = fmaxf(cvh((ushort)(ya.w)) + acc[6] * rd, 0.f);
    o[7] = fmaxf(cvh((ushort)(ya.w >> 16)) + acc[7] * rd, 0.f);
    o[8] = fmaxf(cvh((ushort)(yb.x)) + acc[8] * rd, 0.f);
    o[9] = fmaxf(cvh((ushort)(yb.x >> 16)) + acc[9] * rd, 0.f);
    o[10] = fmaxf(cvh((ushort)(yb.y)) + acc[10] * rd, 0.f);
    o[11] = fmaxf(cvh((ushort)(yb.y >> 16)) + acc[11] * rd, 0.f);
    o[12] = fmaxf(cvh((ushort)(yb.z)) + acc[12] * rd, 0.f);
    o[13] = fmaxf(cvh((ushort)(yb.z >> 16)) + acc[13] * rd, 0.f);
    o[14] = fmaxf(cvh((ushort)(yb.w)) + acc[14] * rd, 0.f);
    o[15] = fmaxf(cvh((ushort)(yb.w >> 16)) + acc[15] * rd, 0.f);
    uint4 wa, wb;
    wa.x = pk2(o[0], o[1]);   wa.y = pk2(o[2], o[3]);
    wa.z = pk2(o[4], o[5]);   wa.w = pk2(o[6], o[7]);
    wb.x = pk2(o[8], o[9]);   wb.y = pk2(o[10], o[11]);
    wb.z = pk2(o[12], o[13]); wb.w = pk2(o[14], o[15]);
    ((uint4*)h16)[n * 2] = wa;
    ((uint4*)h16)[n * 2 + 1] = wb;
  }
}

// ------- gather layer 2 + output GEMM, LDS-resident srclist -----------------
// Block = half-bucket (128 nodes, 256 threads). Stage sorted srclist slice +
// A slice in LDS (gsort1-proven shape); 2 threads/node full-row gather with
// f32 acc; epilogue: thread computes 20 output cols from LDS weights.
__global__ __launch_bounds__(256) void k_gout2(
    const __half* __restrict__ h16, const int* __restrict__ A,
    const int* __restrict__ srclist, const float* __restrict__ wn2,
    const float* __restrict__ ws2, const float* __restrict__ b2,
    float* __restrict__ out) {
  __shared__ int sb[GCAP];
  __shared__ int Aloc[129];
  __shared__ float wns[H * C];
  __shared__ float wss[H * C];
  __shared__ float bs[C];
  const int tid = threadIdx.x;
  const int n0 = blockIdx.x * 128;
  for (int i = tid; i < H * C; i += 256) {
    wns[i] = wn2[i];
    wss[i] = ws2[i];
  }
  if (tid < C) bs[tid] = b2[tid];
  if (tid == 0) Aloc[0] = (n0 == 0) ? 0 : A[n0 - 1];
  if (tid < 128) {
    int nn = n0 + tid;
    if (nn < N_NODES) Aloc[tid + 1] = A[nn];
  }
  __syncthreads();
  const int lastv = (n0 + 127 < N_NODES) ? 127 : (N_NODES - 1 - n0);
  const int base = Aloc[0];
  int cnt = Aloc[lastv + 1] - base;
  if (cnt > GCAP) cnt = GCAP;  // ~impossible; guards LDS
  for (int i = tid; i < cnt; i += 256) sb[i] = srclist[base + i];
  __syncthreads();

  const int nl = tid >> 1, s = tid & 1;
  const int n = n0 + nl;
  if (n >= N_NODES) return;  // no further barriers
  int lo = Aloc[nl] - base, hi = Aloc[nl + 1] - base;
  if (hi > cnt) hi = cnt;
  const uint4* hr = (const uint4*)h16;
  float acc[16];
#pragma unroll
  for (int i = 0; i < 16; ++i) acc[i] = 0.f;
  int e = lo + s;
  for (; e + 6 < hi; e += 8) {  // 4 edges/batch, 8 lines in flight
    int i0 = sb[e], i1 = sb[e + 2], i2 = sb[e + 4], i3 = sb[e + 6];
    uint4 a0 = hr[i0 * 2], b0 = hr[i0 * 2 + 1];
    uint4 a1 = hr[i1 * 2], b1 = hr[i1 * 2 + 1];
    uint4 a2 = hr[i2 * 2], b2v = hr[i2 * 2 + 1];
    uint4 a3 = hr[i3 * 2], b3 = hr[i3 * 2 + 1];
    ACC_ROW(a0, b0) ACC_ROW(a1, b1) ACC_ROW(a2, b2v) ACC_ROW(a3, b3)
  }
  for (; e < hi; e += 2) {
    int i0 = sb[e];
    uint4 a0 = hr[i0 * 2], b0 = hr[i0 * 2 + 1];
    ACC_ROW(a0, b0)
  }
#pragma unroll
  for (int i = 0; i < 16; ++i) acc[i] += __shfl_xor(acc[i], 1);

  // epilogue: this thread computes cols [s*20, s*20+20)
  const float rd = 1.0f / fmaxf((float)(hi - lo), 1.0f);
  uint4 ha = hr[n * 2], hb = hr[n * 2 + 1];
  float hv[16];
  hv[0] = cvh((ushort)(ha.x));  hv[1] = cvh((ushort)(ha.x >> 16));
  hv[2] = cvh((ushort)(ha.y));  hv[3] = cvh((ushort)(ha.y >> 16));
  hv[4] = cvh((ushort)(ha.z));  hv[5] = cvh((ushort)(ha.z >> 16));
  hv[6] = cvh((ushort)(ha.w));  hv[7] = cvh((ushort)(ha.w >> 16));
  hv[8] = cvh((ushort)(hb.x));  hv[9] = cvh((ushort)(hb.x >> 16));
  hv[10] = cvh((ushort)(hb.y)); hv[11] = cvh((ushort)(hb.y >> 16));
  hv[12] = cvh((ushort)(hb.z)); hv[13] = cvh((ushort)(hb.z >> 16));
  hv[14] = cvh((ushort)(hb.w)); hv[15] = cvh((ushort)(hb.w >> 16));
  const int c0 = s * 20;
  float o[20];
#pragma unroll
  for (int j = 0; j < 20; ++j) o[j] = bs[c0 + j];
#pragma unroll
  for (int k = 0; k < H; ++k) {
    float a = hv[k];
    const float* wr = &wss[k * C + c0];
#pragma unroll
    for (int j = 0; j < 20; ++j) o[j] += a * wr[j];
  }
#pragma unroll
  for (int k = 0; k < H; ++k) {
    float m = acc[k] * rd;
    const float* wr = &wns[k * C + c0];
#pragma unroll
    for (int j = 0; j < 20; ++j) o[j] += m * wr[j];
  }
  float* orow = &out[(size_t)n * C + c0];
#pragma unroll
  for (int q = 0; q < 5; ++q)
    *(float4*)&orow[q * 4] =
        make_float4(o[q * 4], o[q * 4 + 1], o[q * 4 + 2], o[q * 4 + 3]);
}

extern "C" void kernel_launch(void* const* d_in, const int* in_sizes, int n_in,
                              void* d_out, int out_size, void* d_ws,
                              size_t ws_size, hipStream_t stream) {
  const float* x = (const float*)d_in[0];
  const int* src = (const int*)d_in[1];
  const int* dst = (const int*)d_in[2];
  const float* wn1 = (const float*)d_in[3];
  const float* ws1 = (const float*)d_in[4];
  const float* b1 = (const float*)d_in[5];
  const float* wn2 = (const float*)d_in[6];
  const float* ws2 = (const float*)d_in[7];
  const float* b2 = (const float*)d_in[8];
  float* out = (float*)d_out;

  // xn1 (fp16, 3.2MB) lives in d_out (consumed by k_gsort1 before k_gout2
  // writes d_out).
  __half* xn1h = (__half*)out;

  // ws layout (float offsets), 13.2 MB total (same byte footprint):
  //   [0, 100000)              A: CSR end offsets (int)
  //   [100000, 100391)         starts (int)
  //   [100391, 100782)         counts (int)
  //   [102400, 102400+E)       P: packed pairs -> sorted srclist in place (int)
  //   [102400+E, +NH/2)        y1 (fp16, NH halves)
  //   [102400+E+NH/2, +NH/2)   h  (fp16, NH halves)
  //   pc (int[256*391] = 400 KB) OVERLAYS the h region (dead after fill).
  float* wsp = (float*)d_ws;
  int* A = (int*)wsp;
  int* starts = (int*)wsp + 100000;
  int* counts = (int*)wsp + 100391;
  int* P = (int*)(wsp + 102400);
  __half* y1h16 = (__half*)(wsp + 102400 + N_EDGES);
  __half* h16 = (__half*)(wsp + 102400 + N_EDGES + NH / 2);
  int* pc = (int*)(wsp + 102400 + N_EDGES + NH / 2);  // overlay on h16

  k_pcount<<<ABLK, 256, 0, stream>>>(dst, pc);
  k_pscanA<<<NBKT, 256, 0, stream>>>(pc, counts);
  k_pscanB<<<1, 512, 0, stream>>>(counts, starts);
  k_fill_proj<<<ABLK + PROJB, 256, 0, stream>>>(x, wn1, ws1, b1, src, dst, pc,
                                                starts, P, xn1h, y1h16);
  k_gsort1<<<NBKT, 512, 0, stream>>>(starts, counts, P, A, xn1h, y1h16, h16);
  k_gout2<<<GBLK, 256, 0, stream>>>(h16, A, P, wn2, ws2, b2, out);
}